// Round 21
// baseline (53.528 us; speedup 1.0000x reference)
//
#include <hip/hip_runtime.h>
#include <hip/hip_bf16.h>

typedef __attribute__((ext_vector_type(8))) __bf16 bf16x8;
typedef __attribute__((ext_vector_type(4))) __bf16 bf16x4;
typedef __attribute__((ext_vector_type(2))) __bf16 bf16x2;
typedef __attribute__((ext_vector_type(4))) float f32x4;
typedef __attribute__((ext_vector_type(16))) float f32x16;
typedef __attribute__((ext_vector_type(2))) int i32x2;

constexpr int S_LEN = 4096;
constexpr int H = 8;
constexpr int HKV = 2;
constexpr int D = 64;
constexpr int BK = 64;                // keys per tile
constexpr int QW = 32;                // q rows per 1-wave block
constexpr int NQG = S_LEN / QW;       // 128 q-groups
constexpr int NKT = S_LEN / BK;       // 64 kv tiles per kv head
// exp2-domain scores; no softmax shift (s <= ~9, common factor cancels).
constexpr float QSCALE = 0.125f * 1.44269504088896f;

__device__ __forceinline__ float fexp2(float x) {
  return __builtin_amdgcn_exp2f(x);   // raw v_exp_f32 (R14 lesson)
}

// XOR swizzle for [*][64] bf16 tiles (K/V): 16B granular.
__device__ __forceinline__ int swz(int row, int col) {
  return (row * 64 + col) ^ ((((row >> 2) ^ row) & 7) << 3);
}

// async DMA global->LDS, 16B per lane; lds base must be wave-uniform.
#define GLOAD_LDS16(g, l)                                        \
  __builtin_amdgcn_global_load_lds(                              \
      (const __attribute__((address_space(1))) void*)(g),        \
      (__attribute__((address_space(3))) void*)(l), 16, 0, 0)

// explicit waits for the single-wave DMA pipeline. "memory" clobber orders
// surrounding memory ops; sched_barrier pins scheduling (guide rule #18).
__device__ __forceinline__ void wait_vmcnt8() {
  asm volatile("s_waitcnt vmcnt(8)" ::: "memory");
  __builtin_amdgcn_sched_barrier(0);
}
__device__ __forceinline__ void wait_vmcnt0() {
  asm volatile("s_waitcnt vmcnt(0)" ::: "memory");
  __builtin_amdgcn_sched_barrier(0);
}
__device__ __forceinline__ void wait_lgkm0() {
  asm volatile("s_waitcnt lgkmcnt(0)" ::: "memory");
  __builtin_amdgcn_sched_barrier(0);
}

__device__ __forceinline__ bf16x8 load8_scaled(const float* p, float scale) {
  f32x4 a = *reinterpret_cast<const f32x4*>(p);
  f32x4 b = *reinterpret_cast<const f32x4*>(p + 4);
  bf16x8 r;
  r[0] = (__bf16)(a[0] * scale); r[1] = (__bf16)(a[1] * scale);
  r[2] = (__bf16)(a[2] * scale); r[3] = (__bf16)(a[3] * scale);
  r[4] = (__bf16)(b[0] * scale); r[5] = (__bf16)(b[1] * scale);
  r[6] = (__bf16)(b[2] * scale); r[7] = (__bf16)(b[3] * scale);
  return r;
}

__device__ __forceinline__ int pk2(float lo, float hi) {
  bf16x2 t;
  t[0] = (__bf16)lo;
  t[1] = (__bf16)hi;
  return __builtin_bit_cast(int, t);
}

// Prepass: pack K -> bf16 [hkv][tile]{swz(kv,d)} and V -> bf16 V^T
// [hkv][tile]{swz(d,kv)} as 8KB blobs == byte-exact LDS tile images.
__global__ __launch_bounds__(256) void pack_kv_kernel(
    const float* __restrict__ k, const float* __restrict__ v,
    __bf16* __restrict__ kp, __bf16* __restrict__ vp) {
  const int tid  = threadIdx.x;
  const int sb   = blockIdx.x & 1;
  const int tile = (blockIdx.x >> 1) & (NKT - 1);
  const int hkv  = blockIdx.x >> 7;
  const int kv0  = tile * BK;
  __bf16* kb = kp + (size_t)(hkv * NKT + tile) * 4096;
  __bf16* vb = vp + (size_t)(hkv * NKT + tile) * 4096;
  {  // K: 32 rows x 64 cols per sub-block, 8 cols/thread, swizzled
    const int row = sb * 32 + (tid >> 3), cg = (tid & 7) * 8;
    const float* src = k + ((size_t)(kv0 + row) * HKV + hkv) * D + cg;
    f32x4 a = *reinterpret_cast<const f32x4*>(src);
    f32x4 b = *reinterpret_cast<const f32x4*>(src + 4);
    bf16x8 w;
    w[0] = (__bf16)a[0]; w[1] = (__bf16)a[1]; w[2] = (__bf16)a[2]; w[3] = (__bf16)a[3];
    w[4] = (__bf16)b[0]; w[5] = (__bf16)b[1]; w[6] = (__bf16)b[2]; w[7] = (__bf16)b[3];
    *reinterpret_cast<bf16x8*>(&kb[swz(row, cg)]) = w;
  }
  {  // V^T: 2 kv x 4 d per thread, in-register transpose, swizzled
    const int kvl = sb * 32 + (tid >> 4) * 2, d0 = (tid & 15) * 4;
    f32x4 lv0 = *reinterpret_cast<const f32x4*>(
        v + ((size_t)(kv0 + kvl) * HKV + hkv) * D + d0);
    f32x4 lv1 = *reinterpret_cast<const f32x4*>(
        v + ((size_t)(kv0 + kvl + 1) * HKV + hkv) * D + d0);
#pragma unroll
    for (int j = 0; j < 4; ++j) {
      bf16x2 vw;
      vw[0] = (__bf16)lv0[j]; vw[1] = (__bf16)lv1[j];
      *reinterpret_cast<bf16x2*>(&vb[swz(d0 + j, kvl)]) = vw;
    }
  }
}

// ONE-WAVE blocks, barrier-free, counted-vmcnt DMA pipeline (T4/T14):
// block = 1 wave owning 32 q-rows + private single-buffered 16KB K/V LDS
// (10 blocks/CU vs ~2 before). Per tile: vmcnt(8)->QK, lgkm0 + issue
// K-DMA(t+1) under exp2, vmcnt(8)->PV, lgkm0 + issue V-DMA(t+1) under
// next tile's QK. All hazards are same-wave (no cross-wave races).
// Inner math identical to R16/R20 (proven): 32x32 swapped MFMA,
// in-register P via permlane32_swap, shift-free exp2.
template <int LOG2C, bool SPLIT, bool PACKED>
__global__ __launch_bounds__(64, 4) void gqa_fwd_kernel(
    const float* __restrict__ q, const float* __restrict__ k,
    const float* __restrict__ v, float* __restrict__ out,
    const __bf16* __restrict__ kp, const __bf16* __restrict__ vp,
    __bf16* __restrict__ po, float* __restrict__ ml) {
  constexpr int TPC = (1 << LOG2C) / BK;  // tiles per full chunk

  const int lane = threadIdx.x & 63;
  const int cl   = lane & 31;   // q column (and MFMA row index)
  const int hi   = lane >> 5;   // k-group half

  const int h = blockIdx.x & 7;
  const int widx = blockIdx.x >> 3;
  int g = 0, c = 0;
  {
    int acc0 = 0;
    for (int gx = NQG - 1; gx >= 0; --gx) {   // heavy q-groups first
      const int n = ((gx * QW + QW - 1) >> LOG2C) + 1;
      if (widx < acc0 + n) { g = gx; c = widx - acc0; break; }
      acc0 += n;
    }
  }
  const int cmax = (g * QW + QW - 1) >> LOG2C;
  const int hkv = h >> 2;
  const int q0w = g * QW;                    // wave's first q row
  const int kb0 = c << LOG2C;
  const int nt  = (c < cmax) ? TPC : (((q0w + 31 - kb0) >> 6) + 1);
  const int qq  = q0w + cl;                  // this lane's q row

  __shared__ __bf16 klds[64 * 64];           // K tile [kv][d], swizzled, 8KB
  __shared__ __bf16 vlds[64 * 64];           // V^T tile [d][kv], swizzled, 8KB

  // ---- Q B-fragments (held), pre-scaled into exp2 domain ----
  bf16x8 qf[4];
#pragma unroll
  for (int s = 0; s < 4; ++s)
    qf[s] = load8_scaled(q + ((size_t)qq * H + h) * D + s * 16 + hi * 8, QSCALE);

  float l_ = 0.0f;                     // lane-pair partial softmax denom
  f32x16 oa[2];
#pragma unroll
  for (int dt = 0; dt < 2; ++dt)
#pragma unroll
    for (int e = 0; e < 16; ++e) oa[dt][e] = 0.f;

  // ---- DMA issue helpers: 8 x 16B/lane = 8KB per call, wave-uniform dest ----
  auto dma_k = [&](int t) {
    const size_t blob = (size_t)(hkv * NKT + (kb0 >> 6) + t) * 4096;
    const char* kg = (const char*)(kp + blob) + (lane << 4);
    char* kl = (char*)&klds[0];
#pragma unroll
    for (int i = 0; i < 8; ++i) GLOAD_LDS16(kg + i * 1024, kl + i * 1024);
  };
  auto dma_v = [&](int t) {
    const size_t blob = (size_t)(hkv * NKT + (kb0 >> 6) + t) * 4096;
    const char* vg = (const char*)(vp + blob) + (lane << 4);
    char* vl = (char*)&vlds[0];
#pragma unroll
    for (int i = 0; i < 8; ++i) GLOAD_LDS16(vg + i * 1024, vl + i * 1024);
  };
  // fallback staging (no workspace): synchronous, same-wave LDS ordering
  auto stage_sync = [&](int t) {
    const int kb = kb0 + t * BK;
#pragma unroll
    for (int j = 0; j < 8; ++j) {
      bf16x8 w = load8_scaled(
          k + ((size_t)(kb + lane) * HKV + hkv) * D + j * 8, 1.0f);
      *reinterpret_cast<bf16x8*>(&klds[swz(lane, j * 8)]) = w;
    }
    const int d0 = (lane & 15) * 4;
#pragma unroll
    for (int u = 0; u < 8; ++u) {
      const int kvl = u * 8 + (lane >> 4) * 2;
      f32x4 lv0 = *reinterpret_cast<const f32x4*>(
          v + ((size_t)(kb + kvl) * HKV + hkv) * D + d0);
      f32x4 lv1 = *reinterpret_cast<const f32x4*>(
          v + ((size_t)(kb + kvl + 1) * HKV + hkv) * D + d0);
#pragma unroll
      for (int j = 0; j < 4; ++j) {
        bf16x2 vw;
        vw[0] = (__bf16)lv0[j]; vw[1] = (__bf16)lv1[j];
        *reinterpret_cast<bf16x2*>(&vlds[swz(d0 + j, kvl)]) = vw;
      }
    }
  };

  if constexpr (PACKED) { dma_k(0); dma_v(0); }

  for (int t = 0; t < nt; ++t) {
    const int kb = kb0 + t * BK;
    if constexpr (!PACKED) stage_sync(t);

    if constexpr (PACKED) wait_vmcnt8();   // K(t) landed; V(t) may be in flight

    // ---- S^T = K Q^T ----
    f32x16 st[2];
#pragma unroll
    for (int kt = 0; kt < 2; ++kt)
#pragma unroll
      for (int e = 0; e < 16; ++e) st[kt][e] = 0.f;
    __builtin_amdgcn_s_setprio(1);
#pragma unroll
    for (int s = 0; s < 4; ++s) {
      bf16x8 kf0 = *reinterpret_cast<const bf16x8*>(&klds[swz(cl, s * 16 + hi * 8)]);
      bf16x8 kf1 = *reinterpret_cast<const bf16x8*>(&klds[swz(32 + cl, s * 16 + hi * 8)]);
      st[0] = __builtin_amdgcn_mfma_f32_32x32x16_bf16(kf0, qf[s], st[0], 0, 0, 0);
      st[1] = __builtin_amdgcn_mfma_f32_32x32x16_bf16(kf1, qf[s], st[1], 0, 0, 0);
    }
    __builtin_amdgcn_s_setprio(0);

    if constexpr (PACKED) {
      wait_lgkm0();                     // K ds_reads retired -> safe overwrite
      if (t + 1 < nt) dma_k(t + 1);     // K-DMA hides under exp2 below
    }

    // causal mask (boundary tiles only; key per C-layout m74/m101)
    if (kb + 63 > q0w) {
#pragma unroll
      for (int kt = 0; kt < 2; ++kt)
#pragma unroll
        for (int rr = 0; rr < 16; ++rr) {
          const int key = kb + 32 * kt + (rr & 3) + 8 * (rr >> 2) + 4 * hi;
          if (key > qq) st[kt][rr] = -1e30f;
        }
    }

    // shift-free exp2 (raw v_exp_f32): branch-free, no max tracking
    float ps0 = 0.f, ps1 = 0.f;
#pragma unroll
    for (int kt = 0; kt < 2; ++kt)
#pragma unroll
      for (int e = 0; e < 8; ++e) {
        const float pa = fexp2(st[kt][e]);
        const float pb = fexp2(st[kt][8 + e]);
        ps0 += pa; ps1 += pb;
        st[kt][e] = pa; st[kt][8 + e] = pb;
      }
    l_ += ps0 + ps1;

    if constexpr (PACKED) {
      if (t + 1 < nt) wait_vmcnt8();    // V(t) landed (K(t+1) in flight = 8)
      else wait_vmcnt0();               // nothing else in flight: drain V(t)
    }

    // ---- O^T += V^T P^T; P fragment via 2 permlane32_swap per k-step ----
    __builtin_amdgcn_s_setprio(1);
#pragma unroll
    for (int s = 0; s < 4; ++s) {
      const int kt = s >> 1;
      const int gq = (s & 1) * 2;
      const int x0 = pk2(st[kt][4 * gq + 0], st[kt][4 * gq + 1]);
      const int x1 = pk2(st[kt][4 * gq + 2], st[kt][4 * gq + 3]);
      const int y0 = pk2(st[kt][4 * gq + 4], st[kt][4 * gq + 5]);
      const int y1 = pk2(st[kt][4 * gq + 6], st[kt][4 * gq + 7]);
      i32x2 w0 = __builtin_amdgcn_permlane32_swap(x0, y0, false, false);
      i32x2 w1 = __builtin_amdgcn_permlane32_swap(x1, y1, false, false);
      int pu[4];
      pu[0] = w0[0]; pu[1] = w1[0]; pu[2] = w0[1]; pu[3] = w1[1];
      bf16x8 pf;
      memcpy(&pf, pu, 16);
      bf16x8 vf0 = *reinterpret_cast<const bf16x8*>(&vlds[swz(cl, s * 16 + hi * 8)]);
      bf16x8 vf1 = *reinterpret_cast<const bf16x8*>(&vlds[swz(32 + cl, s * 16 + hi * 8)]);
      oa[0] = __builtin_amdgcn_mfma_f32_32x32x16_bf16(vf0, pf, oa[0], 0, 0, 0);
      oa[1] = __builtin_amdgcn_mfma_f32_32x32x16_bf16(vf1, pf, oa[1], 0, 0, 0);
    }
    __builtin_amdgcn_s_setprio(0);

    if constexpr (PACKED) {
      wait_lgkm0();                     // V ds_reads retired -> safe overwrite
      if (t + 1 < nt) dma_v(t + 1);     // V-DMA hides under next tile's QK
    }
  }

  // ---- epilogue: l over the lane pair; d rows = 32dt + 8qd + 4hi + j ----
  float lsum = l_ + __shfl_xor(l_, 32, 64);
  if (SPLIT && cmax > 0) {
    // partials share a common (unit) scale -> combine is a plain sum
    __bf16* prow = po + ((size_t)(c * S_LEN + qq) * H + h) * D;
#pragma unroll
    for (int dt = 0; dt < 2; ++dt)
#pragma unroll
      for (int qd = 0; qd < 4; ++qd) {
        bf16x4 pb;
        pb[0] = (__bf16)oa[dt][4 * qd + 0]; pb[1] = (__bf16)oa[dt][4 * qd + 1];
        pb[2] = (__bf16)oa[dt][4 * qd + 2]; pb[3] = (__bf16)oa[dt][4 * qd + 3];
        *reinterpret_cast<bf16x4*>(prow + dt * 32 + qd * 8 + hi * 4) = pb;
      }
    if (lane < 32) ml[(size_t)(c * S_LEN + qq) * H + h] = lsum;
  } else {
    const float inv = 1.0f / lsum;
    float* orow = out + ((size_t)qq * H + h) * D;
#pragma unroll
    for (int dt = 0; dt < 2; ++dt)
#pragma unroll
      for (int qd = 0; qd < 4; ++qd) {
        f32x4 o;
        o[0] = oa[dt][4 * qd + 0] * inv; o[1] = oa[dt][4 * qd + 1] * inv;
        o[2] = oa[dt][4 * qd + 2] * inv; o[3] = oa[dt][4 * qd + 3] * inv;
        *reinterpret_cast<f32x4*>(orow + dt * 32 + qd * 8 + hi * 4) = o;
      }
  }
}

// combine (rows >= CHUNK only): 32 rows/block, 8 threads/row, bf16x8 loads.
// Plain sum of partials (shared scale), normalize, store f32x4 pairs.
template <int LOG2C>
__global__ __launch_bounds__(256) void combine_kernel(
    const __bf16* __restrict__ po, const float* __restrict__ ml,
    float* __restrict__ out) {
  const int tid = threadIdx.x;
  const int rl  = tid >> 3;            // 0..31 row within block
  const int d0  = (tid & 7) * 8;       // 8 bf16 per thread
  const int h   = blockIdx.x & 7;
  const int row = (1 << LOG2C) + (blockIdx.x >> 3) * 32 + rl;
  const int cmax = row >> LOG2C;

  float lsum = 0.f;
  float osum[8];
#pragma unroll
  for (int j = 0; j < 8; ++j) osum[j] = 0.f;
  for (int cc = 0; cc <= cmax; ++cc) {
    const size_t base = (size_t)(cc * S_LEN + row) * H + h;
    lsum += ml[base];
    bf16x8 pv = *reinterpret_cast<const bf16x8*>(po + base * D + d0);
#pragma unroll
    for (int j = 0; j < 8; ++j) osum[j] += (float)pv[j];
  }
  const float inv = 1.0f / lsum;
  float* orow = out + ((size_t)row * H + h) * D + d0;
  f32x4 o0, o1;
  o0[0] = osum[0] * inv; o0[1] = osum[1] * inv;
  o0[2] = osum[2] * inv; o0[3] = osum[3] * inv;
  o1[0] = osum[4] * inv; o1[1] = osum[5] * inv;
  o1[2] = osum[6] * inv; o1[3] = osum[7] * inv;
  *reinterpret_cast<f32x4*>(orow) = o0;
  *reinterpret_cast<f32x4*>(orow + 4) = o1;
}

static int nwork32(int log2c) {
  int s = 0;
  for (int g = 0; g < NQG; ++g)
    s += ((g * QW + QW - 1) >> log2c) + 1;
  return s;
}

extern "C" void kernel_launch(void* const* d_in, const int* in_sizes, int n_in,
                              void* d_out, int out_size, void* d_ws, size_t ws_size,
                              hipStream_t stream) {
  const float* q = (const float*)d_in[0];
  const float* k = (const float*)d_in[1];
  const float* v = (const float*)d_in[2];
  float* out = (float*)d_out;

  const size_t pack_e = (size_t)S_LEN * HKV * D;           // 512K bf16 each
  const size_t pack_b = pack_e * 2 * sizeof(__bf16);       // kp + vp bytes
  auto po_e = [](int ns) { return (size_t)ns * S_LEN * H * D; };
  auto ml_e = [](int ns) { return (size_t)ns * S_LEN * H; };

  __bf16* kp = (__bf16*)d_ws;
  __bf16* vp = kp + pack_e;
  char* rest = (char*)d_ws + pack_b;
  const int npack = 2 * HKV * NKT;  // 256 pack blocks

  if (ws_size >= pack_b + po_e(8) * 2 + ml_e(8) * 4) {
    __bf16* po = (__bf16*)rest;
    float* mlp = (float*)(rest + po_e(8) * 2);
    pack_kv_kernel<<<dim3(npack), dim3(256), 0, stream>>>(k, v, kp, vp);
    gqa_fwd_kernel<9, true, true><<<dim3(8 * nwork32(9)), dim3(64), 0, stream>>>(
        q, k, v, out, kp, vp, po, mlp);
    combine_kernel<9><<<dim3((S_LEN - 512) / 32 * 8), dim3(256), 0, stream>>>(po, mlp, out);
  } else if (ws_size >= pack_b + po_e(4) * 2 + ml_e(4) * 4) {
    __bf16* po = (__bf16*)rest;
    float* mlp = (float*)(rest + po_e(4) * 2);
    pack_kv_kernel<<<dim3(npack), dim3(256), 0, stream>>>(k, v, kp, vp);
    gqa_fwd_kernel<10, true, true><<<dim3(8 * nwork32(10)), dim3(64), 0, stream>>>(
        q, k, v, out, kp, vp, po, mlp);
    combine_kernel<10><<<dim3((S_LEN - 1024) / 32 * 8), dim3(256), 0, stream>>>(po, mlp, out);
  } else if (ws_size >= pack_b) {
    pack_kv_kernel<<<dim3(npack), dim3(256), 0, stream>>>(k, v, kp, vp);
    gqa_fwd_kernel<12, false, true><<<dim3(8 * nwork32(12)), dim3(64), 0, stream>>>(
        q, k, v, out, kp, vp, nullptr, nullptr);
  } else {
    gqa_fwd_kernel<12, false, false><<<dim3(8 * nwork32(12)), dim3(64), 0, stream>>>(
        q, k, v, out, nullptr, nullptr, nullptr, nullptr);
  }
}

// Round 22
// 46.560 us; speedup vs baseline: 1.1497x; 1.1497x over previous
//
#include <hip/hip_runtime.h>
#include <hip/hip_bf16.h>

typedef __attribute__((ext_vector_type(8))) __bf16 bf16x8;
typedef __attribute__((ext_vector_type(4))) __bf16 bf16x4;
typedef __attribute__((ext_vector_type(2))) __bf16 bf16x2;
typedef __attribute__((ext_vector_type(4))) float f32x4;
typedef __attribute__((ext_vector_type(16))) float f32x16;
typedef __attribute__((ext_vector_type(2))) int i32x2;

constexpr int S_LEN = 4096;
constexpr int H = 8;
constexpr int HKV = 2;
constexpr int D = 64;
constexpr int BK = 64;                // keys per tile
constexpr int QW = 32;                // q rows per wave (one 32-col MFMA group)
constexpr int WAVES = 4;              // 256 threads, 128 q rows per block
constexpr int QB_ROWS = QW * WAVES;   // 128
constexpr int NQB = S_LEN / QB_ROWS;  // 32
constexpr int NKT = S_LEN / BK;       // 64 kv tiles per kv head
// exp2-domain scores; no softmax shift (s <= ~9, common factor cancels).
constexpr float QSCALE = 0.125f * 1.44269504088896f;

// raw v_exp_f32 (2^x) — libm exp2f expands to a guarded sequence (R14).
__device__ __forceinline__ float fexp2(float x) {
  return __builtin_amdgcn_exp2f(x);
}

// XOR swizzle for [*][64] bf16 tiles (K/V): 16B granular.
__device__ __forceinline__ int swz(int row, int col) {
  return (row * 64 + col) ^ ((((row >> 2) ^ row) & 7) << 3);
}

// async DMA global->LDS, 16B per lane; lds base must be wave-uniform.
#define GLOAD_LDS16(g, l)                                        \
  __builtin_amdgcn_global_load_lds(                              \
      (const __attribute__((address_space(1))) void*)(g),        \
      (__attribute__((address_space(3))) void*)(l), 16, 0, 0)

__device__ __forceinline__ bf16x8 load8_scaled(const float* p, float scale) {
  f32x4 a = *reinterpret_cast<const f32x4*>(p);
  f32x4 b = *reinterpret_cast<const f32x4*>(p + 4);
  bf16x8 r;
  r[0] = (__bf16)(a[0] * scale); r[1] = (__bf16)(a[1] * scale);
  r[2] = (__bf16)(a[2] * scale); r[3] = (__bf16)(a[3] * scale);
  r[4] = (__bf16)(b[0] * scale); r[5] = (__bf16)(b[1] * scale);
  r[6] = (__bf16)(b[2] * scale); r[7] = (__bf16)(b[3] * scale);
  return r;
}

__device__ __forceinline__ int pk2(float lo, float hi) {
  bf16x2 t;
  t[0] = (__bf16)lo;
  t[1] = (__bf16)hi;
  return __builtin_bit_cast(int, t);
}

// Prepass: pack K -> bf16 [hkv][tile]{swz(kv,d)} and V -> bf16 V^T
// [hkv][tile]{swz(d,kv)} as 8KB blobs == byte-exact LDS tile images.
// 256 blocks (sb bit halves each tile) - pack was latency-bound at 128.
__global__ __launch_bounds__(256) void pack_kv_kernel(
    const float* __restrict__ k, const float* __restrict__ v,
    __bf16* __restrict__ kp, __bf16* __restrict__ vp) {
  const int tid  = threadIdx.x;
  const int sb   = blockIdx.x & 1;
  const int tile = (blockIdx.x >> 1) & (NKT - 1);
  const int hkv  = blockIdx.x >> 7;
  const int kv0  = tile * BK;
  __bf16* kb = kp + (size_t)(hkv * NKT + tile) * 4096;
  __bf16* vb = vp + (size_t)(hkv * NKT + tile) * 4096;
  {  // K: 32 rows x 64 cols per sub-block, 8 cols/thread, swizzled
    const int row = sb * 32 + (tid >> 3), cg = (tid & 7) * 8;
    const float* src = k + ((size_t)(kv0 + row) * HKV + hkv) * D + cg;
    f32x4 a = *reinterpret_cast<const f32x4*>(src);
    f32x4 b = *reinterpret_cast<const f32x4*>(src + 4);
    bf16x8 w;
    w[0] = (__bf16)a[0]; w[1] = (__bf16)a[1]; w[2] = (__bf16)a[2]; w[3] = (__bf16)a[3];
    w[4] = (__bf16)b[0]; w[5] = (__bf16)b[1]; w[6] = (__bf16)b[2]; w[7] = (__bf16)b[3];
    *reinterpret_cast<bf16x8*>(&kb[swz(row, cg)]) = w;
  }
  {  // V^T: 2 kv x 4 d per thread, in-register transpose, swizzled
    const int kvl = sb * 32 + (tid >> 4) * 2, d0 = (tid & 15) * 4;
    f32x4 lv0 = *reinterpret_cast<const f32x4*>(
        v + ((size_t)(kv0 + kvl) * HKV + hkv) * D + d0);
    f32x4 lv1 = *reinterpret_cast<const f32x4*>(
        v + ((size_t)(kv0 + kvl + 1) * HKV + hkv) * D + d0);
#pragma unroll
    for (int j = 0; j < 4; ++j) {
      bf16x2 vw;
      vw[0] = (__bf16)lv0[j]; vw[1] = (__bf16)lv1[j];
      *reinterpret_cast<bf16x2*>(&vb[swz(d0 + j, kvl)]) = vw;
    }
  }
}

// Best-measured configuration (R16/R20, 46.0-46.7 us total): 32x32 MFMA
// core, in-register P (permlane32_swap), shift-free softmax, even-nt 2x
// unroll, K+V both DMA-staged in 32KB double-buffered LDS. 0 bank
// conflicts (R13). (256,3): no VGPR cap squeeze (R6). No device-scope
// fences (R11). Split + separate combine (R8). Structural probes that
// all regressed vs this: head-pairing (R17/R18), V-direct-from-L2 (R19),
// 1-wave counted-vmcnt pipeline (R21) - measured local optimum.
template <int LOG2C, bool SPLIT, bool PACKED>
__global__ __launch_bounds__(256, 3) void gqa_fwd_kernel(
    const float* __restrict__ q, const float* __restrict__ k,
    const float* __restrict__ v, float* __restrict__ out,
    const __bf16* __restrict__ kp, const __bf16* __restrict__ vp,
    __bf16* __restrict__ po, float* __restrict__ ml) {
  constexpr int TPC = (1 << LOG2C) / BK;  // tiles per full chunk (even)

  const int tid  = threadIdx.x;
  const int lane = tid & 63;
  const int wid  = tid >> 6;
  const int cl   = lane & 31;   // q column (and MFMA row index)
  const int hi   = lane >> 5;   // k-group half

  const int h = blockIdx.x & 7;
  const int widx = blockIdx.x >> 3;
  int qb = 0, c = 0;
  {
    int acc0 = 0;
    for (int qx = NQB - 1; qx >= 0; --qx) {   // heavy q-blocks first
      const int n = ((qx * QB_ROWS + QB_ROWS - 1) >> LOG2C) + 1;
      if (widx < acc0 + n) { qb = qx; c = widx - acc0; break; }
      acc0 += n;
    }
  }
  const int cmax = (qb * QB_ROWS + QB_ROWS - 1) >> LOG2C;
  const int hkv = h >> 2;
  const int q0w = qb * QB_ROWS + wid * QW;            // wave's first q row
  const int nt  = (c < cmax) ? TPC : ((QB_ROWS / BK) * (qb + 1) - TPC * cmax);
  const int kb0 = c << LOG2C;
  const int qq  = q0w + cl;                            // this lane's q row

  __shared__ __bf16 klds[2][64 * 64];          // K tile [kv][d], swizzled
  __shared__ __bf16 vlds[2][64 * 64];          // V^T tile [d][kv], swizzled

  // ---- Q B-fragments (held), pre-scaled into exp2 domain ----
  bf16x8 qf[4];
#pragma unroll
  for (int s = 0; s < 4; ++s)
    qf[s] = load8_scaled(q + ((size_t)qq * H + h) * D + s * 16 + hi * 8, QSCALE);

  float l_ = 0.0f;                     // lane-pair partial softmax denom
  f32x16 oa[2];
#pragma unroll
  for (int dt = 0; dt < 2; ++dt)
#pragma unroll
    for (int e = 0; e < 16; ++e) oa[dt][e] = 0.f;

  // ---- staging (byte-exact LDS images via global_load_lds, R8) ----
  const int s16 = tid >> 4;
  const int s4  = (tid & 15) * 4;
  auto stage = [&](int buf, int t) {
    if constexpr (PACKED) {
      const size_t blob = (size_t)(hkv * NKT + (kb0 >> 6) + t) * 4096;
      const char* kg = (const char*)(kp + blob) + wid * 2048 + (lane << 4);
      const char* vg = (const char*)(vp + blob) + wid * 2048 + (lane << 4);
      char* kl = (char*)&klds[buf][0] + wid * 2048;   // wave-uniform base
      char* vl = (char*)&vlds[buf][0] + wid * 2048;
      GLOAD_LDS16(kg, kl);
      GLOAD_LDS16(kg + 1024, kl + 1024);
      GLOAD_LDS16(vg, vl);
      GLOAD_LDS16(vg + 1024, vl + 1024);
    } else {
      const int kb = kb0 + t * BK;
#pragma unroll
      for (int u = 0; u < 4; ++u) {
        f32x4 ka = *reinterpret_cast<const f32x4*>(
            k + ((size_t)(kb + u * 16 + s16) * HKV + hkv) * D + s4);
        bf16x4 kw;
        kw[0] = (__bf16)ka[0]; kw[1] = (__bf16)ka[1];
        kw[2] = (__bf16)ka[2]; kw[3] = (__bf16)ka[3];
        *reinterpret_cast<bf16x4*>(&klds[buf][swz(u * 16 + s16, s4)]) = kw;
      }
      f32x4 lv[4];
#pragma unroll
      for (int u = 0; u < 4; ++u)
        lv[u] = *reinterpret_cast<const f32x4*>(
            v + ((size_t)(kb + s16 * 4 + u) * HKV + hkv) * D + s4);
#pragma unroll
      for (int j = 0; j < 4; ++j) {
        bf16x4 vw;
        vw[0] = (__bf16)lv[0][j]; vw[1] = (__bf16)lv[1][j];
        vw[2] = (__bf16)lv[2][j]; vw[3] = (__bf16)lv[3][j];
        *reinterpret_cast<bf16x4*>(&vlds[buf][swz(s4 + j, s16 * 4)]) = vw;
      }
    }
  };

  // one full tile: QK -> exp2 -> in-register P -> PV, buffer index static
  auto tile_body = [&](int buf, int t) {
    const int kb = kb0 + t * BK;
    if (kb > q0w + 31) return;   // fully masked for this wave (tail tiles)

    f32x16 st[2];
#pragma unroll
    for (int kt = 0; kt < 2; ++kt)
#pragma unroll
      for (int e = 0; e < 16; ++e) st[kt][e] = 0.f;
    __builtin_amdgcn_s_setprio(1);
#pragma unroll
    for (int s = 0; s < 4; ++s) {
      bf16x8 kf0 = *reinterpret_cast<const bf16x8*>(
          &klds[buf][swz(cl, s * 16 + hi * 8)]);
      bf16x8 kf1 = *reinterpret_cast<const bf16x8*>(
          &klds[buf][swz(32 + cl, s * 16 + hi * 8)]);
      st[0] = __builtin_amdgcn_mfma_f32_32x32x16_bf16(kf0, qf[s], st[0], 0, 0, 0);
      st[1] = __builtin_amdgcn_mfma_f32_32x32x16_bf16(kf1, qf[s], st[1], 0, 0, 0);
    }
    __builtin_amdgcn_s_setprio(0);

    // causal mask (boundary tiles only; key per C-layout m74/m101)
    if (kb + 63 > q0w) {
#pragma unroll
      for (int kt = 0; kt < 2; ++kt)
#pragma unroll
        for (int rr = 0; rr < 16; ++rr) {
          const int key = kb + 32 * kt + (rr & 3) + 8 * (rr >> 2) + 4 * hi;
          if (key > qq) st[kt][rr] = -1e30f;
        }
    }

    // shift-free exp2 (raw v_exp_f32): branch-free, no max tracking
    float ps0 = 0.f, ps1 = 0.f;
#pragma unroll
    for (int kt = 0; kt < 2; ++kt)
#pragma unroll
      for (int e = 0; e < 8; ++e) {
        const float pa = fexp2(st[kt][e]);
        const float pb = fexp2(st[kt][8 + e]);
        ps0 += pa; ps1 += pb;
        st[kt][e] = pa; st[kt][8 + e] = pb;
      }
    l_ += ps0 + ps1;

    // O^T += V^T P^T; P fragment via 2 permlane32_swap per k-step (R13)
    __builtin_amdgcn_s_setprio(1);
#pragma unroll
    for (int s = 0; s < 4; ++s) {
      const int kt = s >> 1;
      const int g  = (s & 1) * 2;
      const int x0 = pk2(st[kt][4 * g + 0], st[kt][4 * g + 1]);
      const int x1 = pk2(st[kt][4 * g + 2], st[kt][4 * g + 3]);
      const int y0 = pk2(st[kt][4 * g + 4], st[kt][4 * g + 5]);
      const int y1 = pk2(st[kt][4 * g + 6], st[kt][4 * g + 7]);
      i32x2 w0 = __builtin_amdgcn_permlane32_swap(x0, y0, false, false);
      i32x2 w1 = __builtin_amdgcn_permlane32_swap(x1, y1, false, false);
      int pu[4];
      pu[0] = w0[0]; pu[1] = w1[0]; pu[2] = w0[1]; pu[3] = w1[1];
      bf16x8 pf;
      memcpy(&pf, pu, 16);
      bf16x8 vf0 = *reinterpret_cast<const bf16x8*>(
          &vlds[buf][swz(cl, s * 16 + hi * 8)]);
      bf16x8 vf1 = *reinterpret_cast<const bf16x8*>(
          &vlds[buf][swz(32 + cl, s * 16 + hi * 8)]);
      oa[0] = __builtin_amdgcn_mfma_f32_32x32x16_bf16(vf0, pf, oa[0], 0, 0, 0);
      oa[1] = __builtin_amdgcn_mfma_f32_32x32x16_bf16(vf1, pf, oa[1], 0, 0, 0);
    }
    __builtin_amdgcn_s_setprio(0);
  };

  stage(0, 0);
  __syncthreads();

  for (int t = 0; t < nt; t += 2) {     // nt is even: no tail iteration
    if (t + 1 < nt) stage(1, t + 1);
    tile_body(0, t);
    __syncthreads();
    if (t + 2 < nt) stage(0, t + 2);
    tile_body(1, t + 1);
    __syncthreads();
  }

  // ---- epilogue: l over the lane pair; d rows = 32dt + 8qd + 4hi + j ----
  float lsum = l_ + __shfl_xor(l_, 32, 64);
  if (SPLIT && cmax > 0) {
    // partials share a common (unit) scale -> combine is a plain sum
    __bf16* prow = po + ((size_t)(c * S_LEN + qq) * H + h) * D;
#pragma unroll
    for (int dt = 0; dt < 2; ++dt)
#pragma unroll
      for (int qd = 0; qd < 4; ++qd) {
        bf16x4 pb;
        pb[0] = (__bf16)oa[dt][4 * qd + 0]; pb[1] = (__bf16)oa[dt][4 * qd + 1];
        pb[2] = (__bf16)oa[dt][4 * qd + 2]; pb[3] = (__bf16)oa[dt][4 * qd + 3];
        *reinterpret_cast<bf16x4*>(prow + dt * 32 + qd * 8 + hi * 4) = pb;
      }
    if (lane < 32) ml[(size_t)(c * S_LEN + qq) * H + h] = lsum;
  } else {
    const float inv = 1.0f / lsum;
    float* orow = out + ((size_t)qq * H + h) * D;
#pragma unroll
    for (int dt = 0; dt < 2; ++dt)
#pragma unroll
      for (int qd = 0; qd < 4; ++qd) {
        f32x4 o;
        o[0] = oa[dt][4 * qd + 0] * inv; o[1] = oa[dt][4 * qd + 1] * inv;
        o[2] = oa[dt][4 * qd + 2] * inv; o[3] = oa[dt][4 * qd + 3] * inv;
        *reinterpret_cast<f32x4*>(orow + dt * 32 + qd * 8 + hi * 4) = o;
      }
  }
}

// combine (rows >= CHUNK only): 32 rows/block, 8 threads/row, bf16x8 loads.
// Plain sum of partials (shared scale), normalize, store f32x4 pairs.
template <int LOG2C>
__global__ __launch_bounds__(256) void combine_kernel(
    const __bf16* __restrict__ po, const float* __restrict__ ml,
    float* __restrict__ out) {
  const int tid = threadIdx.x;
  const int rl  = tid >> 3;            // 0..31 row within block
  const int d0  = (tid & 7) * 8;       // 8 bf16 per thread
  const int h   = blockIdx.x & 7;
  const int row = (1 << LOG2C) + (blockIdx.x >> 3) * 32 + rl;
  const int cmax = row >> LOG2C;

  float lsum = 0.f;
  float osum[8];
#pragma unroll
  for (int j = 0; j < 8; ++j) osum[j] = 0.f;
  for (int cc = 0; cc <= cmax; ++cc) {
    const size_t base = (size_t)(cc * S_LEN + row) * H + h;
    lsum += ml[base];
    bf16x8 pv = *reinterpret_cast<const bf16x8*>(po + base * D + d0);
#pragma unroll
    for (int j = 0; j < 8; ++j) osum[j] += (float)pv[j];
  }
  const float inv = 1.0f / lsum;
  float* orow = out + ((size_t)row * H + h) * D + d0;
  f32x4 o0, o1;
  o0[0] = osum[0] * inv; o0[1] = osum[1] * inv;
  o0[2] = osum[2] * inv; o0[3] = osum[3] * inv;
  o1[0] = osum[4] * inv; o1[1] = osum[5] * inv;
  o1[2] = osum[6] * inv; o1[3] = osum[7] * inv;
  *reinterpret_cast<f32x4*>(orow) = o0;
  *reinterpret_cast<f32x4*>(orow + 4) = o1;
}

static int nwork_items(int log2c) {
  int s = 0;
  for (int qb = 0; qb < NQB; ++qb)
    s += ((qb * QB_ROWS + QB_ROWS - 1) >> log2c) + 1;
  return s;
}

extern "C" void kernel_launch(void* const* d_in, const int* in_sizes, int n_in,
                              void* d_out, int out_size, void* d_ws, size_t ws_size,
                              hipStream_t stream) {
  const float* q = (const float*)d_in[0];
  const float* k = (const float*)d_in[1];
  const float* v = (const float*)d_in[2];
  float* out = (float*)d_out;

  const size_t pack_e = (size_t)S_LEN * HKV * D;           // 512K bf16 each
  const size_t pack_b = pack_e * 2 * sizeof(__bf16);       // kp + vp bytes
  auto po_e = [](int ns) { return (size_t)ns * S_LEN * H * D; };
  auto ml_e = [](int ns) { return (size_t)ns * S_LEN * H; };

  __bf16* kp = (__bf16*)d_ws;
  __bf16* vp = kp + pack_e;
  char* rest = (char*)d_ws + pack_b;
  const int npack = 2 * HKV * NKT;  // 256 pack blocks

  if (ws_size >= pack_b + po_e(8) * 2 + ml_e(8) * 4) {
    __bf16* po = (__bf16*)rest;
    float* mlp = (float*)(rest + po_e(8) * 2);
    pack_kv_kernel<<<dim3(npack), dim3(256), 0, stream>>>(k, v, kp, vp);
    gqa_fwd_kernel<9, true, true><<<dim3(8 * nwork_items(9)), dim3(256), 0, stream>>>(
        q, k, v, out, kp, vp, po, mlp);
    combine_kernel<9><<<dim3((S_LEN - 512) / 32 * 8), dim3(256), 0, stream>>>(po, mlp, out);
  } else if (ws_size >= pack_b + po_e(4) * 2 + ml_e(4) * 4) {
    __bf16* po = (__bf16*)rest;
    float* mlp = (float*)(rest + po_e(4) * 2);
    pack_kv_kernel<<<dim3(npack), dim3(256), 0, stream>>>(k, v, kp, vp);
    gqa_fwd_kernel<10, true, true><<<dim3(8 * nwork_items(10)), dim3(256), 0, stream>>>(
        q, k, v, out, kp, vp, po, mlp);
    combine_kernel<10><<<dim3((S_LEN - 1024) / 32 * 8), dim3(256), 0, stream>>>(po, mlp, out);
  } else if (ws_size >= pack_b) {
    pack_kv_kernel<<<dim3(npack), dim3(256), 0, stream>>>(k, v, kp, vp);
    gqa_fwd_kernel<12, false, true><<<dim3(8 * nwork_items(12)), dim3(256), 0, stream>>>(
        q, k, v, out, kp, vp, nullptr, nullptr);
  } else {
    gqa_fwd_kernel<12, false, false><<<dim3(8 * nwork_items(12)), dim3(256), 0, stream>>>(
        q, k, v, out, nullptr, nullptr, nullptr, nullptr);
  }
}